// Round 3
// baseline (170.141 us; speedup 1.0000x reference)
//
#include <hip/hip_runtime.h>
#include <hip/hip_bf16.h>

// ---------------------------------------------------------------------------
// Diagonal-covariance GMM log-likelihoods as one bf16 MFMA GEMM + bias:
//   out[m,k] = sum_f [ x^2 * (-0.5/cov) + x * (mu/cov) ] + bias[k]
// GEMM: M=16384, N=512 (padded from 500), K2=2048 (interleaved x^2/x pairs)
//
// R2: traffic fix — BM=64 x BN=256 (W panel is 2MB => L2-resident everywhere;
//     B-side re-reads become L2 hits; X read ~once). 512 blocks, 2/CU.
//     launch_bounds(256,2) so acc AGPRs don't force spills (R1 post-mortem:
//     (256,4) clamped unified regs to 128 -> per-iter scratch spill -> 290MB
//     WRITE_SIZE). Dense coalesced epilogue via 2-pass 32KB LDS transpose.
// ---------------------------------------------------------------------------

typedef __attribute__((ext_vector_type(8))) __bf16 bf16x8;
typedef __attribute__((ext_vector_type(4))) float  f32x4;

#define LOG_2PI 1.837877066409345339082f

constexpr int M_TOT = 16384;   // B*T
constexpr int F_DIM = 1024;
constexpr int K_GMM = 500;
constexpr int N_PAD = 512;

constexpr int BM  = 64;
constexpr int BN  = 256;
constexpr int BKF = 32;              // K-step in floats (=> 64 bf16 along K2)
constexpr int NIT = F_DIM / BKF;     // 32 K-steps

// pack (bf16(x*x), bf16(x)) into one dword: low16 = x^2 (even K2 slot), hi16 = x
__device__ __forceinline__ unsigned pack_sq_x(float x) {
    __hip_bfloat162 h = __float22bfloat162_rn(make_float2(x * x, x));
    union { __hip_bfloat162 h; unsigned u; } cv;
    cv.h = h;
    return cv.u;
}

// ---------------------------------------------------------------------------
// prep: W[k][2f] = bf16(-0.5/cov), W[k][2f+1] = bf16(mu/cov); bias[k] in fp32.
// Rows k in [500,512) are zeroed (padding), bias=0 there.
// ---------------------------------------------------------------------------
__global__ __launch_bounds__(256) void prep_w_kernel(
    const float* __restrict__ mu, const float* __restrict__ cov,
    unsigned* __restrict__ Wb, float* __restrict__ bias)
{
    const int k = blockIdx.x;
    const int t = threadIdx.x;
    float sl = 0.f, sq = 0.f;
    if (k < K_GMM) {
        #pragma unroll
        for (int j = 0; j < 4; ++j) {
            const int f   = t + j * 256;
            const float c = cov[k * F_DIM + f];
            const float m = mu[k * F_DIM + f];
            const float ic = 1.0f / c;
            __hip_bfloat162 h = __float22bfloat162_rn(make_float2(-0.5f * ic, m * ic));
            union { __hip_bfloat162 h; unsigned u; } cv; cv.h = h;
            Wb[k * F_DIM + f] = cv.u;
            sl += logf(c);
            sq += m * m * ic;
        }
    } else {
        #pragma unroll
        for (int j = 0; j < 4; ++j) Wb[k * F_DIM + t + j * 256] = 0u;
    }
    #pragma unroll
    for (int off = 32; off > 0; off >>= 1) {
        sl += __shfl_down(sl, off, 64);
        sq += __shfl_down(sq, off, 64);
    }
    __shared__ float red[8];
    if ((t & 63) == 0) { red[(t >> 6) * 2] = sl; red[(t >> 6) * 2 + 1] = sq; }
    __syncthreads();
    if (t == 0) {
        const float SL = red[0] + red[2] + red[4] + red[6];
        const float SQ = red[1] + red[3] + red[5] + red[7];
        bias[k] = (k < K_GMM)
                ? (-0.5f * (F_DIM * LOG_2PI) - 0.5f * SL - 0.5f * SQ) : 0.f;
    }
}

// ---------------------------------------------------------------------------
// GEMM: 64x256 tile, 4 waves (2 row-halves x 2 col-halves; each wave 32x128).
// A: X fp32 -> regs -> (x^2,x) bf16 pairs -> LDS (8KB). B: Wb -> regs -> LDS (32KB).
// One-iteration register prefetch; 2 barriers per K-step.
// Epilogue: 2 passes; waves of col-half p dump acc+bias into 32KB fp32 LDS
// tile, then all threads stream dense contiguous float4 rows to out.
// Block mapping: m_tile = bid&255, n_tile = bid>>8 => the n-pair of each
// m-tile is 256 apart in bid (same XCD) -> X panel shared via that L2.
// ---------------------------------------------------------------------------
__global__ __launch_bounds__(256, 2) void gemm_kernel(
    const float* __restrict__ X, const unsigned* __restrict__ Wb,
    const float* __restrict__ bias, float* __restrict__ out)
{
    __shared__ __align__(16) char smem[40960];
    unsigned short* As = reinterpret_cast<unsigned short*>(smem);         // 64 x 64 bf16 = 8 KiB
    unsigned short* Bs = reinterpret_cast<unsigned short*>(smem + 8192);  // 256 x 64 bf16 = 32 KiB
    float*          ep = reinterpret_cast<float*>(smem);                  // 64 x 128 fp32 = 32 KiB (epilogue)

    const int bid    = blockIdx.x;
    const int m_base = (bid & 255) * BM;
    const int n_base = (bid >> 8) * BN;

    const int tid  = threadIdx.x;
    const int lane = tid & 63;
    const int wv   = tid >> 6;
    const int wr   = (wv >> 1) * 32;    // wave's row block in tile (0/32)
    const int wc   = (wv & 1) * 128;    // wave's col block in tile (0/128)
    const int hi   = lane >> 4;         // 0..3
    const int lo   = lane & 15;

    const int srow = tid >> 3;          // staging row (0..31, +i*32)
    const int scol = tid & 7;           // staging 16B chunk within 32-float row

    const float4* Xv = reinterpret_cast<const float4*>(X);
    const uint4*  Wv = reinterpret_cast<const uint4*>(Wb);

    f32x4 acc[2][8];
    #pragma unroll
    for (int a = 0; a < 2; ++a)
        #pragma unroll
        for (int b = 0; b < 8; ++b)
            acc[a][b] = (f32x4){0.f, 0.f, 0.f, 0.f};

    float4 a_reg[2];
    uint4  b_reg[8];
    #pragma unroll
    for (int i = 0; i < 2; ++i)
        a_reg[i] = Xv[(m_base + srow + i * 32) * (F_DIM / 4) + scol];
    #pragma unroll
    for (int i = 0; i < 8; ++i)
        b_reg[i] = Wv[(n_base + srow + i * 32) * (F_DIM / 4) + scol];

    for (int it = 0; it < NIT; ++it) {
        __syncthreads();   // previous iteration's LDS reads complete
        #pragma unroll
        for (int i = 0; i < 2; ++i) {
            const float4 av = a_reg[i];
            uint4 wa;
            wa.x = pack_sq_x(av.x);
            wa.y = pack_sq_x(av.y);
            wa.z = pack_sq_x(av.z);
            wa.w = pack_sq_x(av.w);
            *reinterpret_cast<uint4*>(&As[(srow + i * 32) * 64 + scol * 8]) = wa;
        }
        #pragma unroll
        for (int i = 0; i < 8; ++i)
            *reinterpret_cast<uint4*>(&Bs[(srow + i * 32) * 64 + scol * 8]) = b_reg[i];
        __syncthreads();   // staging visible

        if (it + 1 < NIT) {   // prefetch next K-step; flies during the MFMAs
            const int kf4 = (it + 1) * (BKF / 4);
            #pragma unroll
            for (int i = 0; i < 2; ++i)
                a_reg[i] = Xv[(m_base + srow + i * 32) * (F_DIM / 4) + kf4 + scol];
            #pragma unroll
            for (int i = 0; i < 8; ++i)
                b_reg[i] = Wv[(n_base + srow + i * 32) * (F_DIM / 4) + kf4 + scol];
        }

        #pragma unroll
        for (int c = 0; c < 2; ++c) {   // two K=32 chunks per K-step
            bf16x8 af[2], bfr[8];
            #pragma unroll
            for (int a = 0; a < 2; ++a)
                af[a] = *reinterpret_cast<const bf16x8*>(
                    &As[(wr + a * 16 + lo) * 64 + c * 32 + hi * 8]);
            #pragma unroll
            for (int b = 0; b < 8; ++b)
                bfr[b] = *reinterpret_cast<const bf16x8*>(
                    &Bs[(wc + b * 16 + lo) * 64 + c * 32 + hi * 8]);
            #pragma unroll
            for (int a = 0; a < 2; ++a)
                #pragma unroll
                for (int b = 0; b < 8; ++b)
                    acc[a][b] = __builtin_amdgcn_mfma_f32_16x16x32_bf16(
                        af[a], bfr[b], acc[a][b], 0, 0, 0);
        }
    }

    // ---- Epilogue: two 128-col passes; acc+bias -> LDS -> dense row writes ----
    #pragma unroll
    for (int p = 0; p < 2; ++p) {
        __syncthreads();               // previous LDS use (main loop / pass 0 copy) done
        if ((wv & 1) == p) {           // waves owning col-half p dump their acc
            #pragma unroll
            for (int b = 0; b < 8; ++b) {
                const int col = b * 16 + lo;
                const float bv = bias[n_base + p * 128 + col];
                #pragma unroll
                for (int a = 0; a < 2; ++a) {
                    const int er = wr + a * 16 + hi * 4;  // D: col=lane&15, row=(lane>>4)*4+i
                    #pragma unroll
                    for (int i = 0; i < 4; ++i)
                        ep[(er + i) * 128 + col] = acc[a][b][i] + bv;
                }
            }
        }
        __syncthreads();
        const int c_base = n_base + p * 128;
        const int ncols  = (K_GMM - c_base < 128) ? (K_GMM - c_base) : 128;  // 128 or 116
        const int slot   = tid & 31;    // float4 slot within 128 cols
        const int rgrp   = tid >> 5;    // 0..7
        if (slot * 4 < ncols) {
            #pragma unroll
            for (int j = 0; j < 8; ++j) {
                const int row = j * 8 + rgrp;
                const float4 v = *reinterpret_cast<const float4*>(&ep[row * 128 + slot * 4]);
                *reinterpret_cast<float4*>(
                    &out[(size_t)(m_base + row) * K_GMM + c_base + slot * 4]) = v;
            }
        }
    }
}

extern "C" void kernel_launch(void* const* d_in, const int* in_sizes, int n_in,
                              void* d_out, int out_size, void* d_ws, size_t ws_size,
                              hipStream_t stream)
{
    (void)in_sizes; (void)n_in; (void)out_size; (void)ws_size;
    const float* X   = (const float*)d_in[0];
    const float* mu  = (const float*)d_in[1];
    const float* cov = (const float*)d_in[2];
    float* out = (float*)d_out;

    // workspace: Wb = 512*1024 dwords (2 MiB of bf16 pairs), then bias[512] f32
    unsigned* Wb   = (unsigned*)d_ws;
    float*    bias = (float*)((char*)d_ws + (size_t)N_PAD * F_DIM * 4);

    prep_w_kernel<<<dim3(N_PAD), dim3(256), 0, stream>>>(mu, cov, Wb, bias);
    gemm_kernel<<<dim3((M_TOT / BM) * (N_PAD / BN)), dim3(256), 0, stream>>>(X, Wb, bias, out);
}

// Round 4
// 96.312 us; speedup vs baseline: 1.7666x; 1.7666x over previous
//
#include <hip/hip_runtime.h>
#include <hip/hip_bf16.h>

// ---------------------------------------------------------------------------
// Diagonal-covariance GMM log-likelihoods as one bf16 MFMA GEMM + bias:
//   out[m,k] = sum_f [ x^2 * (-0.5/cov) + x * (mu/cov) ] + bias[k]
// GEMM: M=16384, N=512 (padded from 500), K2=2048 (interleaved x^2/x pairs)
//
// R3: LDS-conflict fix. R0's 16-way bank conflict on fragment ds_read_b128
//     (row*128B stride => bank = hi*4, row drops out) made the LDS unit the
//     serialized resource (~4400 cy/iter/CU vs 320 cy MFMA). Changes:
//     (a) A-tile LDS XOR-swizzled: chunk ^= (row&7)  -> 2-way (free).
//     (b) B-side reads W fragments DIRECTLY from global (W = 2MB, L2-resident
//         on every XCD): per-lane bf16x8 loads, no LDS, no barrier coupling.
//     (c) prefetch footprint: only 4 float4 (R1/R2 spilled 32-reg prefetch:
//         WRITE_SIZE 290-346MB was spill write-through, the canary).
// ---------------------------------------------------------------------------

typedef __attribute__((ext_vector_type(8))) __bf16 bf16x8;
typedef __attribute__((ext_vector_type(4))) float  f32x4;

#define LOG_2PI 1.837877066409345339082f

constexpr int M_TOT = 16384;   // B*T
constexpr int F_DIM = 1024;
constexpr int K_GMM = 500;
constexpr int N_PAD = 512;

constexpr int BM  = 128;
constexpr int BN  = 128;
constexpr int BKF = 32;              // K-step in floats (=> 64 bf16 along K2)
constexpr int NIT = F_DIM / BKF;     // 32 K-steps

// pack (bf16(x*x), bf16(x)) into one dword: low16 = x^2 (even K2 slot), hi16 = x
__device__ __forceinline__ unsigned pack_sq_x(float x) {
    __hip_bfloat162 h = __float22bfloat162_rn(make_float2(x * x, x));
    union { __hip_bfloat162 h; unsigned u; } cv;
    cv.h = h;
    return cv.u;
}

// ---------------------------------------------------------------------------
// prep: W[k][2f] = bf16(-0.5/cov), W[k][2f+1] = bf16(mu/cov); bias[k] in fp32.
// Rows k in [500,512) are zeroed (padding), bias=0 there.
// ---------------------------------------------------------------------------
__global__ __launch_bounds__(256) void prep_w_kernel(
    const float* __restrict__ mu, const float* __restrict__ cov,
    unsigned* __restrict__ Wb, float* __restrict__ bias)
{
    const int k = blockIdx.x;
    const int t = threadIdx.x;
    float sl = 0.f, sq = 0.f;
    if (k < K_GMM) {
        #pragma unroll
        for (int j = 0; j < 4; ++j) {
            const int f   = t + j * 256;
            const float c = cov[k * F_DIM + f];
            const float m = mu[k * F_DIM + f];
            const float ic = 1.0f / c;
            __hip_bfloat162 h = __float22bfloat162_rn(make_float2(-0.5f * ic, m * ic));
            union { __hip_bfloat162 h; unsigned u; } cv; cv.h = h;
            Wb[k * F_DIM + f] = cv.u;
            sl += logf(c);
            sq += m * m * ic;
        }
    } else {
        #pragma unroll
        for (int j = 0; j < 4; ++j) Wb[k * F_DIM + t + j * 256] = 0u;
    }
    #pragma unroll
    for (int off = 32; off > 0; off >>= 1) {
        sl += __shfl_down(sl, off, 64);
        sq += __shfl_down(sq, off, 64);
    }
    __shared__ float red[8];
    if ((t & 63) == 0) { red[(t >> 6) * 2] = sl; red[(t >> 6) * 2 + 1] = sq; }
    __syncthreads();
    if (t == 0) {
        const float SL = red[0] + red[2] + red[4] + red[6];
        const float SQ = red[1] + red[3] + red[5] + red[7];
        bias[k] = (k < K_GMM)
                ? (-0.5f * (F_DIM * LOG_2PI) - 0.5f * SL - 0.5f * SQ) : 0.f;
    }
}

// ---------------------------------------------------------------------------
// GEMM: 128x128 tile, 4 waves (2x2, each 64x64), mfma_f32_16x16x32_bf16.
// A: X fp32 -> regs -> (x^2,x) bf16 -> XOR-swizzled LDS (16KB). B: direct
// per-lane global bf16x8 fragment loads (L2-resident W). 512 blocks, 2/CU,
// all co-resident; n-siblings of an m-tile are 256 apart in bid (same XCD).
// ---------------------------------------------------------------------------
__global__ __launch_bounds__(256, 2) void gemm_kernel(
    const float* __restrict__ X, const unsigned* __restrict__ Wb,
    const float* __restrict__ bias, float* __restrict__ out)
{
    __shared__ __align__(16) char smem[32768];
    unsigned short* As = reinterpret_cast<unsigned short*>(smem); // swizzled [128][64] bf16, 16KB
    float*          ep = reinterpret_cast<float*>(smem);          // 64x128 fp32 epilogue, 32KB

    const int bid    = blockIdx.x;
    const int m_base = (bid & 127) * BM;
    const int n_base = (bid >> 7) * BN;

    const int tid  = threadIdx.x;
    const int lane = tid & 63;
    const int wv   = tid >> 6;
    const int wr   = (wv >> 1) * 64;    // wave row block (0/64)
    const int wc   = (wv & 1) * 64;     // wave col block (0/64)
    const int hi   = lane >> 4;         // 0..3
    const int lo   = lane & 15;

    const int sr = tid >> 1;            // staging row 0..127
    const int sh = tid & 1;             // staging half (chunks 0-3 / 4-7)

    const float4*  Xv = reinterpret_cast<const float4*>(X);    // row = 256 float4
    const bf16x8*  Wf = reinterpret_cast<const bf16x8*>(Wb);   // row = 256 bf16x8

    f32x4 acc[4][4];
    #pragma unroll
    for (int a = 0; a < 4; ++a)
        #pragma unroll
        for (int b = 0; b < 4; ++b)
            acc[a][b] = (f32x4){0.f, 0.f, 0.f, 0.f};

    float4 a_reg[4];
    #pragma unroll
    for (int j = 0; j < 4; ++j)
        a_reg[j] = Xv[(m_base + sr) * (F_DIM / 4) + sh * 4 + j];

    // lane-constant part of the read swizzle: row&7 == lo&7 for fragment rows
    const int lsw = lo & 7;

    for (int it = 0; it < NIT; ++it) {
        __syncthreads();   // previous iteration's LDS reads complete
        #pragma unroll
        for (int j = 0; j < 4; ++j) {
            const int chunk = (sh * 4 + j) ^ (sr & 7);   // XOR swizzle
            const float4 av = a_reg[j];
            uint4 wa;
            wa.x = pack_sq_x(av.x);
            wa.y = pack_sq_x(av.y);
            wa.z = pack_sq_x(av.z);
            wa.w = pack_sq_x(av.w);
            *reinterpret_cast<uint4*>(&As[sr * 64 + chunk * 8]) = wa;
        }
        __syncthreads();   // staging visible

        // B fragments straight from global (L2): 8 x 16B per lane
        bf16x8 bq[8];
        #pragma unroll
        for (int b = 0; b < 4; ++b)
            #pragma unroll
            for (int c = 0; c < 2; ++c)
                bq[b * 2 + c] = Wf[(n_base + wc + b * 16 + lo) * (F_DIM / 4)
                                   + it * 8 + c * 4 + hi];

        if (it + 1 < NIT) {   // small prefetch (16 VGPRs)
            #pragma unroll
            for (int j = 0; j < 4; ++j)
                a_reg[j] = Xv[(m_base + sr) * (F_DIM / 4) + (it + 1) * 8 + sh * 4 + j];
        }

        #pragma unroll
        for (int c = 0; c < 2; ++c) {
            bf16x8 af[4];
            #pragma unroll
            for (int a = 0; a < 4; ++a) {
                const int row   = wr + a * 16 + lo;
                const int chunk = (c * 4 + hi) ^ lsw;    // 2-way max -> free
                af[a] = *reinterpret_cast<const bf16x8*>(&As[row * 64 + chunk * 8]);
            }
            #pragma unroll
            for (int a = 0; a < 4; ++a)
                #pragma unroll
                for (int b = 0; b < 4; ++b)
                    acc[a][b] = __builtin_amdgcn_mfma_f32_16x16x32_bf16(
                        af[a], bq[b * 2 + c], acc[a][b], 0, 0, 0);
        }
    }

    // ---- Epilogue: two 64-row passes; acc+bias -> LDS -> dense row writes ----
    const int ncols = (K_GMM - n_base < BN) ? (K_GMM - n_base) : BN;  // 128 or 116
    #pragma unroll
    for (int p = 0; p < 2; ++p) {
        __syncthreads();               // previous LDS use done
        if ((wv >> 1) == p) {          // the 2 waves owning row-half p dump acc
            #pragma unroll
            for (int b = 0; b < 4; ++b) {
                const int col = wc + b * 16 + lo;
                const float bv = bias[n_base + col];
                #pragma unroll
                for (int a = 0; a < 4; ++a)
                    #pragma unroll
                    for (int i = 0; i < 4; ++i)
                        ep[(a * 16 + hi * 4 + i) * 128 + col] = acc[a][b][i] + bv;
            }
        }
        __syncthreads();
        #pragma unroll
        for (int k = 0; k < 8; ++k) {
            const int f    = k * 256 + tid;   // float4 id in 64x32 grid
            const int row  = f >> 5;
            const int slot = f & 31;
            if (slot * 4 < ncols) {
                const float4 v = *reinterpret_cast<const float4*>(&ep[row * 128 + slot * 4]);
                *reinterpret_cast<float4*>(
                    &out[(size_t)(m_base + p * 64 + row) * K_GMM + n_base + slot * 4]) = v;
            }
        }
    }
}

extern "C" void kernel_launch(void* const* d_in, const int* in_sizes, int n_in,
                              void* d_out, int out_size, void* d_ws, size_t ws_size,
                              hipStream_t stream)
{
    (void)in_sizes; (void)n_in; (void)out_size; (void)ws_size;
    const float* X   = (const float*)d_in[0];
    const float* mu  = (const float*)d_in[1];
    const float* cov = (const float*)d_in[2];
    float* out = (float*)d_out;

    // workspace: Wb = 512*1024 dwords (2 MiB of bf16 pairs), then bias[512] f32
    unsigned* Wb   = (unsigned*)d_ws;
    float*    bias = (float*)((char*)d_ws + (size_t)N_PAD * F_DIM * 4);

    prep_w_kernel<<<dim3(N_PAD), dim3(256), 0, stream>>>(mu, cov, Wb, bias);
    gemm_kernel<<<dim3((M_TOT / BM) * (N_PAD / BN)), dim3(256), 0, stream>>>(X, Wb, bias, out);
}